// Round 2
// baseline (36.208 us; speedup 1.0000x reference)
//
#include <hip/hip_runtime.h>
#include <math.h>

#define NUM_HEADS 16
#define HID_VEC 64
#define DIM_HID 64
#define NUM_GAUSS 251
#define E_FEAT 5
#define W_SCA_COLS 320   // DIM_HID + 256
#define GP 17            // padded LDS row stride for gauss weights (breaks stride-16 bank aliasing)

// ---------------------------------------------------------------------------
// Fully self-contained per-edge kernel. One thread per edge.
//
// Algebraic collapse (verified round 0, absmax 3.9e-3 vs 1.57e-2 threshold):
//   weff[h] = w_vec1[h,:] @ w_edge            (input-independent, 64)
//   vnorm[h] = |weff[h]| * ||unit||   ->  vnorm-block of out_sca = ||unit|| * A[o]
//   out_vec[o,i] = B[o]*unit[i]       ->  output_vec[o] = (gate*B[o])^2 * ||unit||^2
// A,B are recomputed per block (cheap, ~5K FMA) to avoid ANY cross-kernel
// state in d_ws — round-1 post-timing divergence traced to that dependency.
// ---------------------------------------------------------------------------
__global__ __launch_bounds__(256) void edge_kernel(
    const int* __restrict__ idxA,     // [E]
    const int* __restrict__ idxB,     // [E]
    const float* __restrict__ feat,   // [E,5]
    const float* __restrict__ pos,    // [N,3]
    const float* __restrict__ w_edge, // [64]
    const float* __restrict__ w_vec1, // [64,64]
    const float* __restrict__ w_vec2, // [16,64]
    const float* __restrict__ w_sca,  // [16,320]
    const float* __restrict__ w_gate, // [16,16]
    const float* __restrict__ b_gate, // [16]
    float* __restrict__ out,
    int E)
{
    __shared__ float wg[NUM_GAUSS][GP];   // gauss weight slice, transposed: [g][o]
    __shared__ float wt[E_FEAT][16];      // edge-type weight slice, transposed
    __shared__ float gw[256];             // w_gate
    __shared__ float gb[16];
    __shared__ float weff[64];
    __shared__ float As[16], Bs[16];

    const int tid = threadIdx.x;

    // --- stage weights into LDS (all threads participate) ---
    for (int i = tid; i < NUM_GAUSS * 16; i += 256) {
        int g = i >> 4, o = i & 15;
        wg[g][o] = w_sca[o * W_SCA_COLS + DIM_HID + g];
    }
    for (int i = tid; i < E_FEAT * 16; i += 256) {
        int t = i >> 4, o = i & 15;
        wt[t][o] = w_sca[o * W_SCA_COLS + DIM_HID + NUM_GAUSS + t];
    }
    gw[tid] = w_gate[tid];
    if (tid < 16) gb[tid] = b_gate[tid];
    // per-block fold of the input-independent algebra
    if (tid < 64) {
        float s = 0.f;
        #pragma unroll 8
        for (int c = 0; c < 64; ++c) s += w_vec1[tid * 64 + c] * w_edge[c];
        weff[tid] = s;
    }
    __syncthreads();
    if (tid < 16) {
        float a = 0.f, b = 0.f;
        #pragma unroll 8
        for (int k = 0; k < 64; ++k) {
            a += fabsf(weff[k]) * w_sca[tid * W_SCA_COLS + k];
            b += w_vec2[tid * 64 + k] * weff[k];
        }
        As[tid] = a;
        Bs[tid] = b;
    }
    __syncthreads();

    const int e = blockIdx.x * 256 + tid;
    if (e >= E) return;

    const int a = idxA[e];
    const int b = idxB[e];
    const float ax = pos[a * 3 + 0], ay = pos[a * 3 + 1], az = pos[a * 3 + 2];
    const float bx = pos[b * 3 + 0], by = pos[b * 3 + 1], bz = pos[b * 3 + 2];
    const float vx = ax - bx, vy = ay - by, vz = az - bz;
    const float d2 = vx * vx + vy * vy + vz * vz;
    const float d  = sqrtf(d2);
    const float un = d / (d + 1e-7f);      // ||unit||

    float acc[16];
    #pragma unroll
    for (int o = 0; o < 16; ++o) acc[o] = un * As[o];

    // edge-type one-hot block (5 dense cols)
    #pragma unroll
    for (int t = 0; t < E_FEAT; ++t) {
        const float f = feat[e * E_FEAT + t];
        #pragma unroll
        for (int o = 0; o < 16; ++o) acc[o] += f * wt[t][o];
    }

    // Gaussian smearing window: exp(-312.5*(d - 0.04g)^2); |d-off|>0.34 -> <2e-16
    {
        const float STEP = 10.0f / 250.0f;                       // 0.04
        const float INVS = 25.0f;
        const float C2   = -312.5f * 1.44269504088896340736f;    // coeff * log2(e)
        int glo = (int)ceilf((d - 0.34f) * INVS);
        int ghi = (int)floorf((d + 0.34f) * INVS);
        if (glo < 0) glo = 0;
        if (ghi > NUM_GAUSS - 1) ghi = NUM_GAUSS - 1;
        for (int g = glo; g <= ghi; ++g) {
            const float t = d - (float)g * STEP;
            const float w = exp2f(C2 * t * t);
            #pragma unroll
            for (int o = 0; o < 16; ++o) acc[o] += w * wg[g][o];
        }
    }

    // gates -> output_vec[o] = (sigmoid(acc@w_gate^T + b)[o] * B[o])^2 * ||unit||^2
    const float u2 = un * un;
    float outv[16];
    #pragma unroll
    for (int o = 0; o < 16; ++o) {
        float x = gb[o];
        #pragma unroll
        for (int p = 0; p < 16; ++p) x += acc[p] * gw[o * 16 + p];
        const float gate = 1.0f / (1.0f + expf(-x));
        const float gv = gate * Bs[o];
        outv[o] = gv * gv * u2;
    }

    // coalesced stores
    float* o1 = out + (size_t)e * 16;
    float* o2 = out + (size_t)E * 16 + (size_t)e * 16;
    #pragma unroll
    for (int o = 0; o < 16; o += 4) {
        *(float4*)(o1 + o) = make_float4(acc[o], acc[o + 1], acc[o + 2], acc[o + 3]);
        *(float4*)(o2 + o) = make_float4(outv[o], outv[o + 1], outv[o + 2], outv[o + 3]);
    }
}

extern "C" void kernel_launch(void* const* d_in, const int* in_sizes, int n_in,
                              void* d_out, int out_size, void* d_ws, size_t ws_size,
                              hipStream_t stream) {
    const int*   idx    = (const int*)d_in[0];    // [2,E]
    const float* feat   = (const float*)d_in[1];  // [E,5]
    const float* pos    = (const float*)d_in[2];  // [N,3]
    const float* w_edge = (const float*)d_in[3];  // [64,1]
    const float* w_vec1 = (const float*)d_in[4];  // [64,64]
    const float* w_vec2 = (const float*)d_in[5];  // [16,64]
    const float* w_sca  = (const float*)d_in[6];  // [16,320]
    const float* w_gate = (const float*)d_in[7];  // [16,16]
    const float* b_gate = (const float*)d_in[8];  // [16]
    float* out = (float*)d_out;

    const int E = in_sizes[0] / 2;
    const int nblk = (E + 255) / 256;
    edge_kernel<<<nblk, 256, 0, stream>>>(idx, idx + E, feat, pos,
                                          w_edge, w_vec1, w_vec2,
                                          w_sca, w_gate, b_gate, out, E);
}

// Round 3
// 25.552 us; speedup vs baseline: 1.4170x; 1.4170x over previous
//
#include <hip/hip_runtime.h>
#include <math.h>

#define NUM_HEADS 16
#define DIM_HID 64
#define NUM_GAUSS 251
#define E_FEAT 5
#define W_SCA_COLS 320   // DIM_HID + 256
#define GP 20            // padded stride (floats): 80B, 16B-aligned, bank-base pattern spreads 8 ways

// ---------------------------------------------------------------------------
// Self-contained per-edge kernel. One thread per edge.
//
// Algebraic collapse (validated: absmax 3.9e-3 vs 1.57e-2 threshold):
//   weff[h] = w_vec1[h,:] @ w_edge                    (input-independent)
//   vnorm block of out_sca = ||unit|| * A[o],  A = |weff| @ w_sca[:, :64]^T
//   out_vec[o,i] = B[o]*unit[i], B = w_vec2 @ weff -> output_vec = (gate*B)^2*||unit||^2
// A,B recomputed per block in LDS (no d_ws cross-kernel state — round-1 lesson).
//
// Round-3 restructure: kernel was LDS-issue-bound (~544 ds_read_b32/wave).
//   - gauss weights: [g][GP] padded rows, read as 4x ds_read_b128  (288 -> 72)
//   - w_gate / b_gate / edge-type cols: wave-uniform global reads -> s_load
//     (scalar pipe, zero LDS traffic)                              (336 -> 0)
// ---------------------------------------------------------------------------
__global__ __launch_bounds__(256) void edge_kernel(
    const int* __restrict__ idxA,     // [E]
    const int* __restrict__ idxB,     // [E]
    const float* __restrict__ feat,   // [E,5]
    const float* __restrict__ pos,    // [N,3]
    const float* __restrict__ w_edge, // [64]
    const float* __restrict__ w_vec1, // [64,64]
    const float* __restrict__ w_vec2, // [16,64]
    const float* __restrict__ w_sca,  // [16,320]
    const float* __restrict__ w_gate, // [16,16]
    const float* __restrict__ b_gate, // [16]
    float* __restrict__ out,
    int E)
{
    __shared__ __align__(16) float wg[NUM_GAUSS * GP]; // gauss slice, transposed: row g holds 16 heads
    __shared__ __align__(16) float weff[64];
    __shared__ float As[16], Bs[16];

    const int tid = threadIdx.x;

    // --- stage gauss weight slice (contiguous global reads, scattered LDS writes) ---
    for (int j = tid; j < 16 * NUM_GAUSS; j += 256) {
        int o = j / NUM_GAUSS;          // magic-mul
        int g = j - o * NUM_GAUSS;
        wg[g * GP + o] = w_sca[o * W_SCA_COLS + DIM_HID + g];
    }

    // --- per-block fold of input-independent algebra (float4 loads) ---
    if (tid < 64) {
        const float4* wrow = (const float4*)(w_vec1 + tid * 64);
        float s = 0.f;
        #pragma unroll
        for (int c4 = 0; c4 < 16; ++c4) {
            float4 v = wrow[c4];
            // w_edge[..] uniform -> s_load
            s += v.x * w_edge[c4 * 4 + 0] + v.y * w_edge[c4 * 4 + 1]
               + v.z * w_edge[c4 * 4 + 2] + v.w * w_edge[c4 * 4 + 3];
        }
        weff[tid] = s;
    }
    __syncthreads();
    if (tid < 16) {
        const float4* srow = (const float4*)(w_sca + tid * W_SCA_COLS);
        const float4* vrow = (const float4*)(w_vec2 + tid * 64);
        float a = 0.f, b = 0.f;
        #pragma unroll
        for (int k4 = 0; k4 < 16; ++k4) {
            float4 sv = srow[k4];
            float4 vv = vrow[k4];
            float4 wv = *(const float4*)&weff[k4 * 4];
            a += fabsf(wv.x) * sv.x + fabsf(wv.y) * sv.y + fabsf(wv.z) * sv.z + fabsf(wv.w) * sv.w;
            b += wv.x * vv.x + wv.y * vv.y + wv.z * vv.z + wv.w * vv.w;
        }
        As[tid] = a;
        Bs[tid] = b;
    }
    __syncthreads();

    const int e = blockIdx.x * 256 + tid;
    if (e >= E) return;

    const int a = idxA[e];
    const int b = idxB[e];
    const float ax = pos[a * 3 + 0], ay = pos[a * 3 + 1], az = pos[a * 3 + 2];
    const float bx = pos[b * 3 + 0], by = pos[b * 3 + 1], bz = pos[b * 3 + 2];
    const float vx = ax - bx, vy = ay - by, vz = az - bz;
    const float d2 = vx * vx + vy * vy + vz * vz;
    const float d  = sqrtf(d2);
    const float un = d / (d + 1e-7f);      // ||unit||

    float acc[16];
    #pragma unroll
    for (int o = 0; o < 16; ++o) acc[o] = un * As[o];

    // edge-type block: feat vector loads + uniform w_sca cols via s_load
    #pragma unroll
    for (int t = 0; t < E_FEAT; ++t) {
        const float f = feat[e * E_FEAT + t];
        #pragma unroll
        for (int o = 0; o < 16; ++o)
            acc[o] += f * w_sca[o * W_SCA_COLS + DIM_HID + NUM_GAUSS + t];
    }

    // Gaussian smearing window: exp(-312.5*(d-0.04g)^2); |d-off|>0.34 -> <2e-16
    {
        const float STEP = 10.0f / 250.0f;                       // 0.04
        const float INVS = 25.0f;
        const float C2   = -312.5f * 1.44269504088896340736f;    // coeff * log2(e)
        int glo = (int)ceilf((d - 0.34f) * INVS);
        int ghi = (int)floorf((d + 0.34f) * INVS);
        if (glo < 0) glo = 0;
        if (ghi > NUM_GAUSS - 1) ghi = NUM_GAUSS - 1;
        for (int g = glo; g <= ghi; ++g) {
            const float t = d - (float)g * STEP;
            const float w = exp2f(C2 * t * t);
            const float4* row = (const float4*)&wg[g * GP];
            const float4 w0 = row[0], w1 = row[1], w2 = row[2], w3 = row[3];
            acc[0]  += w * w0.x; acc[1]  += w * w0.y; acc[2]  += w * w0.z; acc[3]  += w * w0.w;
            acc[4]  += w * w1.x; acc[5]  += w * w1.y; acc[6]  += w * w1.z; acc[7]  += w * w1.w;
            acc[8]  += w * w2.x; acc[9]  += w * w2.y; acc[10] += w * w2.z; acc[11] += w * w2.w;
            acc[12] += w * w3.x; acc[13] += w * w3.y; acc[14] += w * w3.z; acc[15] += w * w3.w;
        }
    }

    // gates: w_gate/b_gate via uniform s_load; sigmoid via exp2
    const float u2 = un * un;
    const float NL2E = -1.44269504088896340736f;
    float outv[16];
    #pragma unroll
    for (int o = 0; o < 16; ++o) {
        float x = b_gate[o];
        #pragma unroll
        for (int p = 0; p < 16; ++p) x += acc[p] * w_gate[o * 16 + p];
        const float gate = 1.0f / (1.0f + exp2f(NL2E * x));
        const float gv = gate * Bs[o];
        outv[o] = gv * gv * u2;
    }

    // coalesced stores (2 x 64B per thread)
    float* o1 = out + (size_t)e * 16;
    float* o2 = out + (size_t)E * 16 + (size_t)e * 16;
    #pragma unroll
    for (int o = 0; o < 16; o += 4) {
        *(float4*)(o1 + o) = make_float4(acc[o], acc[o + 1], acc[o + 2], acc[o + 3]);
        *(float4*)(o2 + o) = make_float4(outv[o], outv[o + 1], outv[o + 2], outv[o + 3]);
    }
}

extern "C" void kernel_launch(void* const* d_in, const int* in_sizes, int n_in,
                              void* d_out, int out_size, void* d_ws, size_t ws_size,
                              hipStream_t stream) {
    const int*   idx    = (const int*)d_in[0];    // [2,E]
    const float* feat   = (const float*)d_in[1];  // [E,5]
    const float* pos    = (const float*)d_in[2];  // [N,3]
    const float* w_edge = (const float*)d_in[3];  // [64,1]
    const float* w_vec1 = (const float*)d_in[4];  // [64,64]
    const float* w_vec2 = (const float*)d_in[5];  // [16,64]
    const float* w_sca  = (const float*)d_in[6];  // [16,320]
    const float* w_gate = (const float*)d_in[7];  // [16,16]
    const float* b_gate = (const float*)d_in[8];  // [16]
    float* out = (float*)d_out;

    const int E = in_sizes[0] / 2;
    const int nblk = (E + 255) / 256;
    edge_kernel<<<nblk, 256, 0, stream>>>(idx, idx + E, feat, pos,
                                          w_edge, w_vec1, w_vec2,
                                          w_sca, w_gate, b_gate, out, E);
}